// Round 15
// baseline (223.132 us; speedup 1.0000x reference)
//
#include <hip/hip_runtime.h>
#include <hip/hip_bf16.h>

// LinearAttention on MI355X (gfx950). Inputs/outputs fp32; internal bf16 MFMA.
// B=4 N=4096 C=1024 H=16 D=64.
//  K0 cvt3:           xb/wqkvb/wprojb = bf16(x / w_qkv / w_proj)   (one kernel)
//  K1 gemm8p<16384>:  QKV^T[c,m] = sum_k w_qkv[c,k]*x[m,k], relu c<2048 rows.
//  K2 ctx_kernel:     per (b,h,s): partial ctx[d,e] = sum_n V[d,n]K[e,n] + ksum.
//  K3 out_kernel:     O[m, h*64+d] = z[n] * sum_e ctx[d,e] Q[e,n]   (bf16)
//  K4 gemm8p<1024>:   out[m,co] = sum_c O[m,c] w_proj[co,c] + b_proj[co] (fp32)
// Deterministic: no atomics; every ws region fully written before read.

typedef __bf16 bf16;
typedef __bf16 bf16x8 __attribute__((ext_vector_type(8)));
typedef __bf16 bf16x4 __attribute__((ext_vector_type(4)));
typedef float  f32x4  __attribute__((ext_vector_type(4)));
typedef float  f32x16 __attribute__((ext_vector_type(16)));

#define MFMA16(a, b, c) __builtin_amdgcn_mfma_f32_16x16x32_bf16((a), (b), (c), 0, 0, 0)
#define MFMA32(a, b, c) __builtin_amdgcn_mfma_f32_32x32x16_bf16((a), (b), (c), 0, 0, 0)

__device__ __forceinline__ void gload_lds16(const bf16* g, bf16* l) {
  // 16B per lane; LDS dest = wave-uniform base + lane*16 (linear layout required).
  __builtin_amdgcn_global_load_lds(
      (const __attribute__((address_space(1))) void*)g,
      (__attribute__((address_space(3))) void*)l, 16, 0, 0);
}

// ---------------------------------------------------------------------------
// K0: fused fp32 -> bf16 convert of x (4194304 f4), w_qkv (786432 f4),
//     w_proj (262144 f4). Grid-stride over the 5242880-f4 virtual concat.
// ---------------------------------------------------------------------------
__global__ __launch_bounds__(256) void cvt3(const float* __restrict__ x,  bf16* __restrict__ xb,
                                            const float* __restrict__ wq, bf16* __restrict__ wqb,
                                            const float* __restrict__ wp, bf16* __restrict__ wpb) {
  const long stride = (long)gridDim.x * 256;
  for (long i4 = (long)blockIdx.x * 256 + threadIdx.x; i4 < 5242880; i4 += stride) {
    const float* s; bf16* d; long off;
    if (i4 < 4194304)      { s = x;  d = xb;  off = i4; }
    else if (i4 < 4980736) { s = wq; d = wqb; off = i4 - 4194304; }
    else                   { s = wp; d = wpb; off = i4 - 4980736; }
    const float4 v = *(const float4*)(s + off * 4);
    bf16x4 o;
    o[0] = (bf16)v.x; o[1] = (bf16)v.y; o[2] = (bf16)v.z; o[3] = (bf16)v.w;
    *(bf16x4*)(d + off * 4) = o;
  }
}

// ---------------------------------------------------------------------------
// gemm8p (32x32x16 MFMA shape) — C[i,j] = sum_k A[i,k]*B[j,k], K=1024.
// 256x256 tile, BK=64, 8 waves (2M x 4N), per-wave 128x64 output as a
// 4x2 grid of 32x32 MFMA tiles, 4 k-steps of 16 per K-tile.
// Rationale (m119): 32x32 shape hits 99.8% of dense MFMA peak vs 87% for
// 16x16, and halves MFMA instruction count (32x8cy vs 64x5cy) -> less
// issue pressure. LDS bytes/reads identical to the 16x16 version.
// Skeleton per tile t (R13's proven race-free concentrated ledger):
//   stage ALL 8 loads of tile t+1 into buf e; vmcnt(8) retires exactly
//   tile t's 8 loads (one full tile of latency cover; never drains
//   mid-loop, T4); barrier; compiler-scheduled body (24 ds_read_b128 +
//   32 MFMA) under setprio(1); lgkmcnt(0); barrier.
// LDS: [dbuf][half] 128 rows x 64 k, XOR chunk swizzle phys=c^(row&7) via
// pre-swizzled global source + linear dest (rule #21; 0 conflicts).
// Frag layouts (guide §3, m74/m101): A/B lane=row(l&31), k=(l>>5)*8+j;
// C/D col=lane&31, row=(reg&3)+8*(reg>>2)+4*(lane>>5).
// Grid dim3(N/256, M/256), 512 threads. Natural block order (R6 affinity).
// ---------------------------------------------------------------------------
template <int LDC, typename CO>
__global__ __launch_bounds__(512, 2) void gemm8p(const bf16* __restrict__ A,
                                                 const bf16* __restrict__ Bm,
                                                 CO* __restrict__ Co,
                                                 const float* __restrict__ bias,
                                                 const int reluRows) {
  __shared__ bf16 As[2][2][8192];   // [dbuf][Mhalf][128r x 64k swizzled]
  __shared__ bf16 Bs[2][2][8192];
  const int tid = threadIdx.x, lane = tid & 63, w = tid >> 6;
  const int wm = w >> 2;            // 2 M-halves
  const int wn = w & 3;             // 4 N-quarters
  const int i0 = blockIdx.y * 256;
  const int j0 = blockIdx.x * 256;

  // Staging: wave w covers rows w*16 + q*8 .. +7 of a 128-row half-tile.
  // lane l -> row +(l>>3), phys chunk l&7; source logical chunk (l&7)^(l>>3).
  const int lr = lane >> 3, lc = (lane & 7) ^ lr;
  const bf16* Ags = A  + (long)(i0 + w * 16 + lr) * 1024 + lc * 8;
  const bf16* Bgs = Bm + (long)(j0 + w * 16 + lr) * 1024 + lc * 8;
  const int ldst = w * 16 * 64;     // + q*512

  const int r31 = lane & 31, g1 = lane >> 5;
  const int x7 = r31 & 7;
  const int bcol = (wn & 1) * 64;   // wave's 64-col strip inside Bs[d][wn>>1]

  f32x16 acc[4][2] = {};

#define STG_A(dd, h, kt, q) \
  gload_lds16(Ags + (long)(h) * 131072 + (q) * 8192 + (kt) * 64, &As[dd][h][ldst + (q) * 512])
#define STG_B(dd, h, kt, q) \
  gload_lds16(Bgs + (long)(h) * 131072 + (q) * 8192 + (kt) * 64, &Bs[dd][h][ldst + (q) * 512])
#define STG_TILE(dd, kt)                                 \
  do {                                                   \
    STG_A(dd, 0, kt, 0); STG_A(dd, 0, kt, 1);            \
    STG_A(dd, 1, kt, 0); STG_A(dd, 1, kt, 1);            \
    STG_B(dd, 0, kt, 0); STG_B(dd, 0, kt, 1);            \
    STG_B(dd, 1, kt, 0); STG_B(dd, 1, kt, 1);            \
  } while (0)

  // Prologue: stage tile 0 fully into dbuf 0 (8 loads/wave outstanding).
  STG_TILE(0, 0);

  for (int t = 0; t < 16; ++t) {
    const int d = t & 1, e = d ^ 1;
    const bf16* Ah = &As[d][wm][0];
    const bf16* Bh = &Bs[d][wn >> 1][0];

    // ---- stage tile t+1; vmcnt(8) retires ALL of tile t ----
    if (t < 15) {
      STG_TILE(e, t + 1);
      asm volatile("s_waitcnt vmcnt(8)" ::: "memory");
    } else {
      asm volatile("s_waitcnt vmcnt(0)" ::: "memory");
    }
    __builtin_amdgcn_s_barrier();       // tile t fully visible to all waves
    __builtin_amdgcn_sched_barrier(0);  // no ds_read hoists above

    // ---- compute body: compiler-scheduled reads + MFMAs ----
    __builtin_amdgcn_s_setprio(1);
#pragma unroll
    for (int ks = 0; ks < 4; ++ks) {    // k-step of 16
      const int ck = ((ks * 2 + g1) ^ x7) * 8;
      bf16x8 af[4], bfr[2];
#pragma unroll
      for (int fm = 0; fm < 4; ++fm)
        af[fm] = *(const bf16x8*)(Ah + (fm * 32 + r31) * 64 + ck);
#pragma unroll
      for (int fn = 0; fn < 2; ++fn)
        bfr[fn] = *(const bf16x8*)(Bh + (bcol + fn * 32 + r31) * 64 + ck);
#pragma unroll
      for (int fm = 0; fm < 4; ++fm)
#pragma unroll
        for (int fn = 0; fn < 2; ++fn)
          acc[fm][fn] = MFMA32(af[fm], bfr[fn], acc[fm][fn]);
    }
    __builtin_amdgcn_s_setprio(0);

    // ---- tail: my reads complete, then join ----
    asm volatile("s_waitcnt lgkmcnt(0)" ::: "memory");
    __builtin_amdgcn_sched_barrier(0);
    __builtin_amdgcn_s_barrier();       // all reads of buf[d] complete
    __builtin_amdgcn_sched_barrier(0);
  }
#undef STG_TILE
#undef STG_A
#undef STG_B

  // Epilogue. 32x32 C/D layout: col = lane&31, row = (r&3)+8*(r>>2)+4*(lane>>5).
  const bool doRelu = (i0 < reluRows);
#pragma unroll
  for (int fm = 0; fm < 4; ++fm) {
#pragma unroll
    for (int fn = 0; fn < 2; ++fn) {
      const int cc = j0 + wn * 64 + fn * 32 + r31;
      const float bv = bias ? bias[cc] : 0.0f;
#pragma unroll
      for (int r = 0; r < 16; ++r) {
        const int row = i0 + wm * 128 + fm * 32 + (r & 3) + 8 * (r >> 2) + 4 * g1;
        float v = acc[fm][fn][r] + bv;
        if (doRelu) v = fmaxf(v, 0.0f);
        Co[(long)row * LDC + cc] = (CO)v;
      }
    }
  }
}

// ---------------------------------------------------------------------------
// K2: per (b,h) n-chunk s (512 cols): partial ctx[d,e] += V[d,n]K[e,n],
// partial ksum[e] += K[e,n] (ones-MFMA). K/V staged to LDS in 128-n chunks
// with coalesced 256B row segments; XOR chunk swizzle c^(row&7) via
// pre-swizzled global source + linear LDS dest; frag reads 2-way (free).
// ---------------------------------------------------------------------------
__global__ __launch_bounds__(256) void ctx_kernel(const bf16* __restrict__ QKV,
                                                  float* __restrict__ ctx_part,
                                                  float* __restrict__ ksum_part) {
  __shared__ bf16 Kl[64 * 128];   // [e][n] swizzled, 16 KiB
  __shared__ bf16 Vl[64 * 128];   // [d][n] swizzled
  const int bh = blockIdx.x;  // 0..63
  const int s  = blockIdx.y;  // 0..7
  const int b  = bh >> 4, h = bh & 15;
  const int tid = threadIdx.x, lane = tid & 63, w = tid >> 6;
  const long ldq = 16384;
  const bf16* Kp = QKV + (long)(1024 + h * 64) * ldq + b * 4096 + s * 512;
  const bf16* Vp = QKV + (long)(2048 + h * 64) * ldq + b * 4096 + s * 512;
  const int r15 = lane & 15, g = lane >> 4;
  const int x7 = r15 & 7;

  long soff[4]; int dofs[4];
#pragma unroll
  for (int j = 0; j < 4; ++j) {
    const int row = w * 16 + j * 4 + g;
    soff[j] = (long)row * ldq + ((lane & 15) ^ (row & 7)) * 8;
    dofs[j] = (w * 16 + j * 4) * 128;
  }
  const int vrow = (w * 16 + r15) * 128;

  bf16x8 ones;
#pragma unroll
  for (int i = 0; i < 8; ++i) ones[i] = (bf16)1.0f;

  f32x4 acc[4]   = {};   // ctx: wave w owns d rows [w*16, w*16+16), 4 e-tiles
  f32x4 accks[4] = {};   // ksum via ones-MFMA (rows identical)

  for (int cc = 0; cc < 4; ++cc) {   // 4 n-chunks of 128
#pragma unroll
    for (int j = 0; j < 4; ++j) {
      gload_lds16(Kp + soff[j] + cc * 128, Kl + dofs[j]);
      gload_lds16(Vp + soff[j] + cc * 128, Vl + dofs[j]);
    }
    __syncthreads();   // vmcnt drained before barrier (compiler)
#pragma unroll
    for (int nk = 0; nk < 4; ++nk) {
      const int ch = ((nk * 4 + g) ^ x7) * 8;
      const bf16x8 av = *(const bf16x8*)(Vl + vrow + ch);
#pragma unroll
      for (int u = 0; u < 4; ++u) {
        const bf16x8 kb = *(const bf16x8*)(Kl + (u * 16 + r15) * 128 + ch);
        acc[u]   = MFMA16(av,   kb, acc[u]);
        accks[u] = MFMA16(ones, kb, accks[u]);
      }
    }
    __syncthreads();
  }

  float* cp = ctx_part + (long)(bh * 8 + s) * 4096;
#pragma unroll
  for (int u = 0; u < 4; ++u)
#pragma unroll
    for (int jj = 0; jj < 4; ++jj) {
      const int d = w * 16 + g * 4 + jj;
      const int e = u * 16 + r15;
      cp[d * 64 + e] = acc[u][jj];
    }
  if (w == 0 && g == 0) {   // row 0 of accks = ksum[e], replicated
#pragma unroll
    for (int u = 0; u < 4; ++u)
      ksum_part[(bh * 8 + s) * 64 + u * 16 + r15] = accks[u][0];
  }
}

// ---------------------------------------------------------------------------
// K3: per (b,h), 256-col n-chunk: O[(b,n), h*64+d] = z[n]*sum_e ctx[d,e]Q[e,n]
// Grid (bh, nc): same-bh blocks 64 apart (64%8==0) -> one XCD -> ctx_part
// slab (128 KB) L2-resident across its 16 readers.
// ---------------------------------------------------------------------------
__global__ __launch_bounds__(256) void out_kernel(const bf16* __restrict__ QKV,
                                                  const float* __restrict__ ctx_part,
                                                  const float* __restrict__ ksum_part,
                                                  bf16* __restrict__ O) {
  __shared__ bf16 ctx_lds[64 * 88];   // [d][e], stride 88 (176B, 16B-mult, ~2-way)
  __shared__ bf16 qlds[256 * 80];     // [n_local][e], stride 80 (160B, 16B-mult)
  __shared__ float ksum_lds[64];
  __shared__ float zlds[256];

  const int bh = blockIdx.x;  // 0..63
  const int nc = blockIdx.y;  // 0..15
  const int b = bh >> 4, h = bh & 15;
  const int tid = threadIdx.x, lane = tid & 63, w = tid >> 6;
  const int n0 = nc * 256;
  const long ldq = 16384;

  // 1) sum 8 ctx partials -> bf16 LDS
  const float* cp = ctx_part + (long)bh * 8 * 4096;
#pragma unroll
  for (int r = 0; r < 16; ++r) {
    const int idx = tid + r * 256;  // = d*64 + e
    float v = 0.0f;
#pragma unroll
    for (int s2 = 0; s2 < 8; ++s2) v += cp[s2 * 4096 + idx];
    ctx_lds[(idx >> 6) * 88 + (idx & 63)] = (bf16)v;
  }
  if (tid < 64) {
    float v = 0.0f;
#pragma unroll
    for (int s2 = 0; s2 < 8; ++s2) v += ksum_part[(bh * 8 + s2) * 64 + tid];
    ksum_lds[tid] = v;
  }
  // 2) stage Q tile transposed: qlds[n][e]
  {
    const bf16* Qp = QKV + (long)(h * 64) * ldq + b * 4096 + n0;
    const int e = tid >> 2, seg = tid & 3;
    const bf16* qr = Qp + (long)e * ldq + seg * 64;
#pragma unroll
    for (int i = 0; i < 64; i += 8) {
      const bf16x8 v = *(const bf16x8*)(qr + i);
#pragma unroll
      for (int jj = 0; jj < 8; ++jj) qlds[(seg * 64 + i + jj) * 80 + e] = v[jj];
    }
  }
  __syncthreads();

  // 3) z[n] = 1/(ksum . Q[:,n] + eps)  — bf16x8 vectorized
  {
    float a = 0.0f;
    const bf16* qrow = qlds + tid * 80;
#pragma unroll
    for (int d0 = 0; d0 < 64; d0 += 8) {
      const bf16x8 qv = *(const bf16x8*)(qrow + d0);
#pragma unroll
      for (int jj = 0; jj < 8; ++jj) a += (float)qv[jj] * ksum_lds[d0 + jj];
    }
    zlds[tid] = 1.0f / (a + 1.1920929e-07f);
  }
  // A-frags (ctx) once per wave: 4 d-tiles x 2 k(e)-steps
  const int r15 = lane & 15;
  const int koff = (lane >> 4) * 8;
  bf16x8 afr[4][2];
#pragma unroll
  for (int t = 0; t < 4; ++t)
#pragma unroll
    for (int s2 = 0; s2 < 2; ++s2)
      afr[t][s2] = *(const bf16x8*)(ctx_lds + (t * 16 + r15) * 88 + s2 * 32 + koff);
  __syncthreads();

  // 4) each wave: 4 n-tiles of 16
#pragma unroll
  for (int nt = 0; nt < 4; ++nt) {
    const int ntile = w * 4 + nt;
    bf16x8 bfr[2];
#pragma unroll
    for (int s2 = 0; s2 < 2; ++s2)
      bfr[s2] = *(const bf16x8*)(qlds + (ntile * 16 + r15) * 80 + s2 * 32 + koff);
    f32x4 accn[4] = {};
#pragma unroll
    for (int t = 0; t < 4; ++t) {
      accn[t] = MFMA16(afr[t][0], bfr[0], accn[t]);
      accn[t] = MFMA16(afr[t][1], bfr[1], accn[t]);
    }
    const int ncol = n0 + ntile * 16 + r15;
    const float zv = zlds[ntile * 16 + r15];
    bf16* orow = O + (long)(b * 4096 + ncol) * 1024 + h * 64;
#pragma unroll
    for (int t = 0; t < 4; ++t) {
      const int d0 = t * 16 + (lane >> 4) * 4;
      bf16x4 pk;
#pragma unroll
      for (int jj = 0; jj < 4; ++jj) pk[jj] = (bf16)(accn[t][jj] * zv);
      *(bf16x4*)(orow + d0) = pk;  // 8B store, 4 consecutive d
    }
  }
}

// ---------------------------------------------------------------------------
extern "C" void kernel_launch(void* const* d_in, const int* in_sizes, int n_in,
                              void* d_out, int out_size, void* d_ws, size_t ws_size,
                              hipStream_t stream) {
  const float* x      = (const float*)d_in[0];  // [4,4096,1024] fp32
  const float* w_qkv  = (const float*)d_in[1];  // [3072,1024]   fp32
  const float* w_proj = (const float*)d_in[2];  // [1024,1024]   fp32
  const float* b_proj = (const float*)d_in[3];  // [1024]        fp32
  float* out = (float*)d_out;                   // [4,4096,1024] fp32

  char* ws = (char*)d_ws;
  // Layout (xb region reused for O after K1):
  bf16*  QKV       = (bf16*)ws;                               // 96 MiB
  float* ctx_part  = (float*)(ws + 100663296);                // 8 MiB
  float* ksum_part = (float*)(ws + 100663296 + 8388608);      // 128 KiB
  bf16*  xb        = (bf16*)(ws + 109182976);                 // 32 MiB (K1 input)
  bf16*  O         = xb;                                      // reuse after K1
  bf16*  wqkvb     = (bf16*)(ws + 109182976 + 33554432);      // 6 MiB
  bf16*  wprojb    = (bf16*)(ws + 109182976 + 33554432 + 6291456);  // 2 MiB

  // K0: fused fp32 -> bf16 conversions
  cvt3<<<2048, 256, 0, stream>>>(x, xb, w_qkv, wqkvb, w_proj, wprojb);
  // K1: QKV^T[c,m] = sum_k w_qkv[c,k]*x[m,k]; relu rows c<2048. M=3072, N=16384.
  gemm8p<16384, bf16><<<dim3(64, 12), 512, 0, stream>>>(wqkvb, xb, QKV, nullptr, 2048);
  // K2: partial ctx + ksum (LDS-staged coalesced)
  ctx_kernel<<<dim3(64, 8), 256, 0, stream>>>(QKV, ctx_part, ksum_part);
  // K3: O[m, c]  (overwrites xb region — xb dead after K1); grid (bh, nc)
  out_kernel<<<dim3(64, 16), 256, 0, stream>>>(QKV, ctx_part, ksum_part, O);
  // K4: out[m,co] = sum_c O[m,c]*w_proj[co,c] + b_proj. M=16384, N=1024, fp32 out.
  gemm8p<1024, float><<<dim3(4, 64), 512, 0, stream>>>(O, wprojb, out, b_proj, 0);
}

// Round 16
// 212.494 us; speedup vs baseline: 1.0501x; 1.0501x over previous
//
#include <hip/hip_runtime.h>
#include <hip/hip_bf16.h>

// LinearAttention on MI355X (gfx950). Inputs/outputs fp32; internal bf16 MFMA.
// B=4 N=4096 C=1024 H=16 D=64.
//  K0 cvt3:            xb/wqkvb/wprojb = bf16(x / w_qkv / w_proj)  (one kernel)
//  K1 gemm8p32<16384>: QKV^T[c,m] = sum_k w_qkv[c,k]*x[m,k], relu c<2048 rows.
//                      32x32x16 MFMA (m119: 99.8% shape efficiency; R15: -6us
//                      vs 16x16 despite structural 4-way frag-read conflict).
//  K2 ctx_kernel:      per (b,h,s): partial ctx[d,e] = sum_n V[d,n]K[e,n] + ksum.
//  K3 out_kernel:      O[m, h*64+d] = z[n] * sum_e ctx[d,e] Q[e,n]  (bf16)
//  K4 gemm8p16<1024>:  out[m,co] = sum_c O[m,c] w_proj[co,c] + b_proj (fp32).
//                      16x16x32 MFMA: K4 is 1 block/CU (256 blocks) -> no
//                      inter-block TLP to hide the 32x32 conflict stalls
//                      (R15: 32x32 cost ~10us here). 0-conflict 16x16 wins.
// Deterministic: no atomics; every ws region fully written before read.

typedef __bf16 bf16;
typedef __bf16 bf16x8 __attribute__((ext_vector_type(8)));
typedef __bf16 bf16x4 __attribute__((ext_vector_type(4)));
typedef float  f32x4  __attribute__((ext_vector_type(4)));
typedef float  f32x16 __attribute__((ext_vector_type(16)));

#define MFMA16(a, b, c) __builtin_amdgcn_mfma_f32_16x16x32_bf16((a), (b), (c), 0, 0, 0)
#define MFMA32(a, b, c) __builtin_amdgcn_mfma_f32_32x32x16_bf16((a), (b), (c), 0, 0, 0)

__device__ __forceinline__ void gload_lds16(const bf16* g, bf16* l) {
  // 16B per lane; LDS dest = wave-uniform base + lane*16 (linear layout required).
  __builtin_amdgcn_global_load_lds(
      (const __attribute__((address_space(1))) void*)g,
      (__attribute__((address_space(3))) void*)l, 16, 0, 0);
}

// ---------------------------------------------------------------------------
// K0: fused fp32 -> bf16 convert of x (4194304 f4), w_qkv (786432 f4),
//     w_proj (262144 f4). Grid-stride over the 5242880-f4 virtual concat.
// ---------------------------------------------------------------------------
__global__ __launch_bounds__(256) void cvt3(const float* __restrict__ x,  bf16* __restrict__ xb,
                                            const float* __restrict__ wq, bf16* __restrict__ wqb,
                                            const float* __restrict__ wp, bf16* __restrict__ wpb) {
  const long stride = (long)gridDim.x * 256;
  for (long i4 = (long)blockIdx.x * 256 + threadIdx.x; i4 < 5242880; i4 += stride) {
    const float* s; bf16* d; long off;
    if (i4 < 4194304)      { s = x;  d = xb;  off = i4; }
    else if (i4 < 4980736) { s = wq; d = wqb; off = i4 - 4194304; }
    else                   { s = wp; d = wpb; off = i4 - 4980736; }
    const float4 v = *(const float4*)(s + off * 4);
    bf16x4 o;
    o[0] = (bf16)v.x; o[1] = (bf16)v.y; o[2] = (bf16)v.z; o[3] = (bf16)v.w;
    *(bf16x4*)(d + off * 4) = o;
  }
}

// ---------------------------------------------------------------------------
// Shared gemm skeleton (R13's proven race-free concentrated ledger):
// per K-tile t: stage ALL 8 loads of tile t+1 into buf e; vmcnt(8) retires
// exactly tile t's 8 loads (one full tile of latency cover; never drains
// mid-loop, T4); barrier; compiler-scheduled body under setprio(1);
// lgkmcnt(0); barrier (buf-reuse safety).
// LDS: [dbuf][half] 128 rows x 64 k, XOR chunk swizzle phys=c^(row&7) via
// pre-swizzled global source + linear dest (rule #21).
// Grid dim3(N/256, M/256), 512 threads. Natural block order (R6 affinity).
// ---------------------------------------------------------------------------

#define STG_A(dd, h, kt, q) \
  gload_lds16(Ags + (long)(h) * 131072 + (q) * 8192 + (kt) * 64, &As[dd][h][ldst + (q) * 512])
#define STG_B(dd, h, kt, q) \
  gload_lds16(Bgs + (long)(h) * 131072 + (q) * 8192 + (kt) * 64, &Bs[dd][h][ldst + (q) * 512])
#define STG_TILE(dd, kt)                                 \
  do {                                                   \
    STG_A(dd, 0, kt, 0); STG_A(dd, 0, kt, 1);            \
    STG_A(dd, 1, kt, 0); STG_A(dd, 1, kt, 1);            \
    STG_B(dd, 0, kt, 0); STG_B(dd, 0, kt, 1);            \
    STG_B(dd, 1, kt, 0); STG_B(dd, 1, kt, 1);            \
  } while (0)

// K1 variant: 32x32x16 MFMA. acc = f32x16[4][2].
template <int LDC, typename CO>
__global__ __launch_bounds__(512, 2) void gemm8p32(const bf16* __restrict__ A,
                                                   const bf16* __restrict__ Bm,
                                                   CO* __restrict__ Co,
                                                   const float* __restrict__ bias,
                                                   const int reluRows) {
  __shared__ bf16 As[2][2][8192];   // [dbuf][Mhalf][128r x 64k swizzled]
  __shared__ bf16 Bs[2][2][8192];
  const int tid = threadIdx.x, lane = tid & 63, w = tid >> 6;
  const int wm = w >> 2;            // 2 M-halves
  const int wn = w & 3;             // 4 N-quarters
  const int i0 = blockIdx.y * 256;
  const int j0 = blockIdx.x * 256;

  const int lr = lane >> 3, lc = (lane & 7) ^ lr;
  const bf16* Ags = A  + (long)(i0 + w * 16 + lr) * 1024 + lc * 8;
  const bf16* Bgs = Bm + (long)(j0 + w * 16 + lr) * 1024 + lc * 8;
  const int ldst = w * 16 * 64;     // + q*512

  const int r31 = lane & 31, g1 = lane >> 5;
  const int x7 = r31 & 7;
  const int bcol = (wn & 1) * 64;   // wave's 64-col strip inside Bs[d][wn>>1]

  f32x16 acc[4][2] = {};

  STG_TILE(0, 0);

  for (int t = 0; t < 16; ++t) {
    const int d = t & 1, e = d ^ 1;
    const bf16* Ah = &As[d][wm][0];
    const bf16* Bh = &Bs[d][wn >> 1][0];

    if (t < 15) {
      STG_TILE(e, t + 1);
      asm volatile("s_waitcnt vmcnt(8)" ::: "memory");
    } else {
      asm volatile("s_waitcnt vmcnt(0)" ::: "memory");
    }
    __builtin_amdgcn_s_barrier();
    __builtin_amdgcn_sched_barrier(0);

    __builtin_amdgcn_s_setprio(1);
#pragma unroll
    for (int ks = 0; ks < 4; ++ks) {    // k-step of 16
      const int ck = ((ks * 2 + g1) ^ x7) * 8;
      bf16x8 af[4], bfr[2];
#pragma unroll
      for (int fm = 0; fm < 4; ++fm)
        af[fm] = *(const bf16x8*)(Ah + (fm * 32 + r31) * 64 + ck);
#pragma unroll
      for (int fn = 0; fn < 2; ++fn)
        bfr[fn] = *(const bf16x8*)(Bh + (bcol + fn * 32 + r31) * 64 + ck);
#pragma unroll
      for (int fm = 0; fm < 4; ++fm)
#pragma unroll
        for (int fn = 0; fn < 2; ++fn)
          acc[fm][fn] = MFMA32(af[fm], bfr[fn], acc[fm][fn]);
    }
    __builtin_amdgcn_s_setprio(0);

    asm volatile("s_waitcnt lgkmcnt(0)" ::: "memory");
    __builtin_amdgcn_sched_barrier(0);
    __builtin_amdgcn_s_barrier();
    __builtin_amdgcn_sched_barrier(0);
  }

  // Epilogue. 32x32 C/D layout: col = lane&31, row = (r&3)+8*(r>>2)+4*(lane>>5).
  const bool doRelu = (i0 < reluRows);
#pragma unroll
  for (int fm = 0; fm < 4; ++fm) {
#pragma unroll
    for (int fn = 0; fn < 2; ++fn) {
      const int cc = j0 + wn * 64 + fn * 32 + r31;
      const float bv = bias ? bias[cc] : 0.0f;
#pragma unroll
      for (int r = 0; r < 16; ++r) {
        const int row = i0 + wm * 128 + fm * 32 + (r & 3) + 8 * (r >> 2) + 4 * g1;
        float v = acc[fm][fn][r] + bv;
        if (doRelu) v = fmaxf(v, 0.0f);
        Co[(long)row * LDC + cc] = (CO)v;
      }
    }
  }
}

// K4 variant: 16x16x32 MFMA (0 LDS conflicts; best for 1-block/CU shapes).
template <int LDC, typename CO>
__global__ __launch_bounds__(512, 2) void gemm8p16(const bf16* __restrict__ A,
                                                   const bf16* __restrict__ Bm,
                                                   CO* __restrict__ Co,
                                                   const float* __restrict__ bias,
                                                   const int reluRows) {
  __shared__ bf16 As[2][2][8192];
  __shared__ bf16 Bs[2][2][8192];
  const int tid = threadIdx.x, lane = tid & 63, w = tid >> 6;
  const int wm = w >> 2;
  const int wn = w & 3;
  const int i0 = blockIdx.y * 256;
  const int j0 = blockIdx.x * 256;

  const int lr = lane >> 3, lc = (lane & 7) ^ lr;
  const bf16* Ags = A  + (long)(i0 + w * 16 + lr) * 1024 + lc * 8;
  const bf16* Bgs = Bm + (long)(j0 + w * 16 + lr) * 1024 + lc * 8;
  const int ldst = w * 16 * 64;

  const int r15 = lane & 15, g = lane >> 4;
  const int ck0 = (g ^ (r15 & 7)) * 8;
  const int ck1 = ((4 + g) ^ (r15 & 7)) * 8;
  const int bbase = ((wn & 1) * 64 + r15) * 64;

  f32x4 acc[8][4] = {};

  STG_TILE(0, 0);

  for (int t = 0; t < 16; ++t) {
    const int d = t & 1, e = d ^ 1;
    const bf16* Ah = &As[d][wm][0];
    const bf16* Bh = &Bs[d][wn >> 1][0];

    if (t < 15) {
      STG_TILE(e, t + 1);
      asm volatile("s_waitcnt vmcnt(8)" ::: "memory");
    } else {
      asm volatile("s_waitcnt vmcnt(0)" ::: "memory");
    }
    __builtin_amdgcn_s_barrier();
    __builtin_amdgcn_sched_barrier(0);

    __builtin_amdgcn_s_setprio(1);
#pragma unroll
    for (int ks = 0; ks < 2; ++ks) {
      const int ck = ks ? ck1 : ck0;
      bf16x8 af[8], bfr[4];
#pragma unroll
      for (int fm = 0; fm < 8; ++fm)
        af[fm] = *(const bf16x8*)(Ah + (fm * 16 + r15) * 64 + ck);
#pragma unroll
      for (int fn = 0; fn < 4; ++fn)
        bfr[fn] = *(const bf16x8*)(Bh + bbase + fn * 1024 + ck);
#pragma unroll
      for (int fm = 0; fm < 8; ++fm)
#pragma unroll
        for (int fn = 0; fn < 4; ++fn)
          acc[fm][fn] = MFMA16(af[fm], bfr[fn], acc[fm][fn]);
    }
    __builtin_amdgcn_s_setprio(0);

    asm volatile("s_waitcnt lgkmcnt(0)" ::: "memory");
    __builtin_amdgcn_sched_barrier(0);
    __builtin_amdgcn_s_barrier();
    __builtin_amdgcn_sched_barrier(0);
  }

  // D layout per 16x16 tile: row = g*4 + jj, col = r15.
  const bool doRelu = (i0 < reluRows);
#pragma unroll
  for (int fm = 0; fm < 8; ++fm) {
    const int r0 = i0 + wm * 128 + fm * 16 + g * 4;
#pragma unroll
    for (int fn = 0; fn < 4; ++fn) {
      const int cc = j0 + wn * 64 + fn * 16 + r15;
      const float bv = bias ? bias[cc] : 0.0f;
#pragma unroll
      for (int jj = 0; jj < 4; ++jj) {
        float v = acc[fm][fn][jj] + bv;
        if (doRelu) v = fmaxf(v, 0.0f);
        Co[(long)(r0 + jj) * LDC + cc] = (CO)v;
      }
    }
  }
}

#undef STG_TILE
#undef STG_A
#undef STG_B

// ---------------------------------------------------------------------------
// K2: per (b,h) n-chunk s (512 cols): partial ctx[d,e] += V[d,n]K[e,n],
// partial ksum[e] += K[e,n] (ones-MFMA). K/V staged to LDS in 128-n chunks
// with coalesced 256B row segments; XOR chunk swizzle c^(row&7) via
// pre-swizzled global source + linear LDS dest; frag reads 2-way (free).
// ---------------------------------------------------------------------------
__global__ __launch_bounds__(256) void ctx_kernel(const bf16* __restrict__ QKV,
                                                  float* __restrict__ ctx_part,
                                                  float* __restrict__ ksum_part) {
  __shared__ bf16 Kl[64 * 128];   // [e][n] swizzled, 16 KiB
  __shared__ bf16 Vl[64 * 128];   // [d][n] swizzled
  const int bh = blockIdx.x;  // 0..63
  const int s  = blockIdx.y;  // 0..7
  const int b  = bh >> 4, h = bh & 15;
  const int tid = threadIdx.x, lane = tid & 63, w = tid >> 6;
  const long ldq = 16384;
  const bf16* Kp = QKV + (long)(1024 + h * 64) * ldq + b * 4096 + s * 512;
  const bf16* Vp = QKV + (long)(2048 + h * 64) * ldq + b * 4096 + s * 512;
  const int r15 = lane & 15, g = lane >> 4;
  const int x7 = r15 & 7;

  long soff[4]; int dofs[4];
#pragma unroll
  for (int j = 0; j < 4; ++j) {
    const int row = w * 16 + j * 4 + g;
    soff[j] = (long)row * ldq + ((lane & 15) ^ (row & 7)) * 8;
    dofs[j] = (w * 16 + j * 4) * 128;
  }
  const int vrow = (w * 16 + r15) * 128;

  bf16x8 ones;
#pragma unroll
  for (int i = 0; i < 8; ++i) ones[i] = (bf16)1.0f;

  f32x4 acc[4]   = {};   // ctx: wave w owns d rows [w*16, w*16+16), 4 e-tiles
  f32x4 accks[4] = {};   // ksum via ones-MFMA (rows identical)

  for (int cc = 0; cc < 4; ++cc) {   // 4 n-chunks of 128
#pragma unroll
    for (int j = 0; j < 4; ++j) {
      gload_lds16(Kp + soff[j] + cc * 128, Kl + dofs[j]);
      gload_lds16(Vp + soff[j] + cc * 128, Vl + dofs[j]);
    }
    __syncthreads();   // vmcnt drained before barrier (compiler)
#pragma unroll
    for (int nk = 0; nk < 4; ++nk) {
      const int ch = ((nk * 4 + g) ^ x7) * 8;
      const bf16x8 av = *(const bf16x8*)(Vl + vrow + ch);
#pragma unroll
      for (int u = 0; u < 4; ++u) {
        const bf16x8 kb = *(const bf16x8*)(Kl + (u * 16 + r15) * 128 + ch);
        acc[u]   = MFMA16(av,   kb, acc[u]);
        accks[u] = MFMA16(ones, kb, accks[u]);
      }
    }
    __syncthreads();
  }

  float* cp = ctx_part + (long)(bh * 8 + s) * 4096;
#pragma unroll
  for (int u = 0; u < 4; ++u)
#pragma unroll
    for (int jj = 0; jj < 4; ++jj) {
      const int d = w * 16 + g * 4 + jj;
      const int e = u * 16 + r15;
      cp[d * 64 + e] = acc[u][jj];
    }
  if (w == 0 && g == 0) {   // row 0 of accks = ksum[e], replicated
#pragma unroll
    for (int u = 0; u < 4; ++u)
      ksum_part[(bh * 8 + s) * 64 + u * 16 + r15] = accks[u][0];
  }
}

// ---------------------------------------------------------------------------
// K3: per (b,h), 256-col n-chunk: O[(b,n), h*64+d] = z[n]*sum_e ctx[d,e]Q[e,n]
// Grid (bh, nc): same-bh blocks 64 apart (64%8==0) -> one XCD -> ctx_part
// slab (128 KB) L2-resident across its 16 readers.
// ---------------------------------------------------------------------------
__global__ __launch_bounds__(256) void out_kernel(const bf16* __restrict__ QKV,
                                                  const float* __restrict__ ctx_part,
                                                  const float* __restrict__ ksum_part,
                                                  bf16* __restrict__ O) {
  __shared__ bf16 ctx_lds[64 * 88];   // [d][e], stride 88 (176B, 16B-mult, ~2-way)
  __shared__ bf16 qlds[256 * 80];     // [n_local][e], stride 80 (160B, 16B-mult)
  __shared__ float ksum_lds[64];
  __shared__ float zlds[256];

  const int bh = blockIdx.x;  // 0..63
  const int nc = blockIdx.y;  // 0..15
  const int b = bh >> 4, h = bh & 15;
  const int tid = threadIdx.x, lane = tid & 63, w = tid >> 6;
  const int n0 = nc * 256;
  const long ldq = 16384;

  // 1) sum 8 ctx partials -> bf16 LDS
  const float* cp = ctx_part + (long)bh * 8 * 4096;
#pragma unroll
  for (int r = 0; r < 16; ++r) {
    const int idx = tid + r * 256;  // = d*64 + e
    float v = 0.0f;
#pragma unroll
    for (int s2 = 0; s2 < 8; ++s2) v += cp[s2 * 4096 + idx];
    ctx_lds[(idx >> 6) * 88 + (idx & 63)] = (bf16)v;
  }
  if (tid < 64) {
    float v = 0.0f;
#pragma unroll
    for (int s2 = 0; s2 < 8; ++s2) v += ksum_part[(bh * 8 + s2) * 64 + tid];
    ksum_lds[tid] = v;
  }
  // 2) stage Q tile transposed: qlds[n][e]
  {
    const bf16* Qp = QKV + (long)(h * 64) * ldq + b * 4096 + n0;
    const int e = tid >> 2, seg = tid & 3;
    const bf16* qr = Qp + (long)e * ldq + seg * 64;
#pragma unroll
    for (int i = 0; i < 64; i += 8) {
      const bf16x8 v = *(const bf16x8*)(qr + i);
#pragma unroll
      for (int jj = 0; jj < 8; ++jj) qlds[(seg * 64 + i + jj) * 80 + e] = v[jj];
    }
  }
  __syncthreads();

  // 3) z[n] = 1/(ksum . Q[:,n] + eps)  — bf16x8 vectorized
  {
    float a = 0.0f;
    const bf16* qrow = qlds + tid * 80;
#pragma unroll
    for (int d0 = 0; d0 < 64; d0 += 8) {
      const bf16x8 qv = *(const bf16x8*)(qrow + d0);
#pragma unroll
      for (int jj = 0; jj < 8; ++jj) a += (float)qv[jj] * ksum_lds[d0 + jj];
    }
    zlds[tid] = 1.0f / (a + 1.1920929e-07f);
  }
  // A-frags (ctx) once per wave: 4 d-tiles x 2 k(e)-steps
  const int r15 = lane & 15;
  const int koff = (lane >> 4) * 8;
  bf16x8 afr[4][2];
#pragma unroll
  for (int t = 0; t < 4; ++t)
#pragma unroll
    for (int s2 = 0; s2 < 2; ++s2)
      afr[t][s2] = *(const bf16x8*)(ctx_lds + (t * 16 + r15) * 88 + s2 * 32 + koff);
  __syncthreads();

  // 4) each wave: 4 n-tiles of 16
#pragma unroll
  for (int nt = 0; nt < 4; ++nt) {
    const int ntile = w * 4 + nt;
    bf16x8 bfr[2];
#pragma unroll
    for (int s2 = 0; s2 < 2; ++s2)
      bfr[s2] = *(const bf16x8*)(qlds + (ntile * 16 + r15) * 80 + s2 * 32 + koff);
    f32x4 accn[4] = {};
#pragma unroll
    for (int t = 0; t < 4; ++t) {
      accn[t] = MFMA16(afr[t][0], bfr[0], accn[t]);
      accn[t] = MFMA16(afr[t][1], bfr[1], accn[t]);
    }
    const int ncol = n0 + ntile * 16 + r15;
    const float zv = zlds[ntile * 16 + r15];
    bf16* orow = O + (long)(b * 4096 + ncol) * 1024 + h * 64;
#pragma unroll
    for (int t = 0; t < 4; ++t) {
      const int d0 = t * 16 + (lane >> 4) * 4;
      bf16x4 pk;
#pragma unroll
      for (int jj = 0; jj < 4; ++jj) pk[jj] = (bf16)(accn[t][jj] * zv);
      *(bf16x4*)(orow + d0) = pk;  // 8B store, 4 consecutive d
    }
  }
}

// ---------------------------------------------------------------------------
extern "C" void kernel_launch(void* const* d_in, const int* in_sizes, int n_in,
                              void* d_out, int out_size, void* d_ws, size_t ws_size,
                              hipStream_t stream) {
  const float* x      = (const float*)d_in[0];  // [4,4096,1024] fp32
  const float* w_qkv  = (const float*)d_in[1];  // [3072,1024]   fp32
  const float* w_proj = (const float*)d_in[2];  // [1024,1024]   fp32
  const float* b_proj = (const float*)d_in[3];  // [1024]        fp32
  float* out = (float*)d_out;                   // [4,4096,1024] fp32

  char* ws = (char*)d_ws;
  // Layout (xb region reused for O after K1):
  bf16*  QKV       = (bf16*)ws;                               // 96 MiB
  float* ctx_part  = (float*)(ws + 100663296);                // 8 MiB
  float* ksum_part = (float*)(ws + 100663296 + 8388608);      // 128 KiB
  bf16*  xb        = (bf16*)(ws + 109182976);                 // 32 MiB (K1 input)
  bf16*  O         = xb;                                      // reuse after K1
  bf16*  wqkvb     = (bf16*)(ws + 109182976 + 33554432);      // 6 MiB
  bf16*  wprojb    = (bf16*)(ws + 109182976 + 33554432 + 6291456);  // 2 MiB

  // K0: fused fp32 -> bf16 conversions
  cvt3<<<2048, 256, 0, stream>>>(x, xb, w_qkv, wqkvb, w_proj, wprojb);
  // K1: QKV^T[c,m] = sum_k w_qkv[c,k]*x[m,k]; relu rows c<2048. M=3072, N=16384.
  gemm8p32<16384, bf16><<<dim3(64, 12), 512, 0, stream>>>(wqkvb, xb, QKV, nullptr, 2048);
  // K2: partial ctx + ksum (LDS-staged coalesced)
  ctx_kernel<<<dim3(64, 8), 256, 0, stream>>>(QKV, ctx_part, ksum_part);
  // K3: O[m, c]  (overwrites xb region — xb dead after K1); grid (bh, nc)
  out_kernel<<<dim3(64, 16), 256, 0, stream>>>(QKV, ctx_part, ksum_part, O);
  // K4: out[m,co] = sum_c O[m,c]*w_proj[co,c] + b_proj. M=16384, N=1024, fp32 out.
  gemm8p16<1024, float><<<dim3(4, 64), 512, 0, stream>>>(O, wprojb, out, b_proj, 0);
}